// Round 4
// baseline (332.298 us; speedup 1.0000x reference)
//
#include <hip/hip_runtime.h>

// ChannelAttention (XCA): B=4, N=8192, C=512, heads=4, dh=128. FP32 in/out.
// R4: fused fp32->bf16 staging in QKV, XCD swizzle, v operand-swap epilogue,
//     norms fused as atomics into QKV epilogue, S split-K=16.

typedef unsigned short ushort_t;
typedef __attribute__((ext_vector_type(8))) short short8;
typedef __attribute__((ext_vector_type(4))) float float4v;
typedef __attribute__((ext_vector_type(4))) unsigned short ushort4v;

__device__ __forceinline__ float bf2f(ushort_t b) {
  union { unsigned u; float f; } c; c.u = ((unsigned)b) << 16; return c.f;
}
__device__ __forceinline__ ushort_t f2bf(float f) {
  union { float f; unsigned u; } c; c.f = f;
  unsigned u = c.u;
  u += 0x7fffu + ((u >> 16) & 1u);   // RNE
  return (ushort_t)(u >> 16);
}

typedef const __attribute__((address_space(1))) unsigned int guint_t;
typedef __attribute__((address_space(3))) unsigned int luint_t;
__device__ __forceinline__ void gl_lds16(const ushort_t* g, ushort_t* l) {
  __builtin_amdgcn_global_load_lds((guint_t*)g, (luint_t*)l, 16, 0, 0);
}

// fp32 -> bf16 for Wqkv (196608 groups of 4) and Wout (65536 groups).
__global__ __launch_bounds__(256) void convert_w(
    const float* __restrict__ w1, const float* __restrict__ w2,
    ushort_t* __restrict__ w1b, ushort_t* __restrict__ w2b) {
  int g = blockIdx.x * 256 + threadIdx.x;
  const float* src; ushort_t* dst; int off;
  if (g < 196608) { src = w1; dst = w1b; off = g; }
  else            { src = w2; dst = w2b; off = g - 196608; }
  size_t e = (size_t)off * 4;
  float4v f = *(const float4v*)(src + e);
  ushort4v o;
#pragma unroll
  for (int i = 0; i < 4; ++i) o[i] = f2bf(f[i]);
  *(ushort4v*)(dst + e) = o;
}

// QKV K-loop: A = x fp32 (reg-prefetch + convert + ds_write), B = Wqkv bf16 (gl_lds).
// SWAP=true computes D = B.A (for v blocks: rows=channel, cols=token).
template <bool SWAP>
__device__ __forceinline__ void qkv_kloop(
    const float* ga, const ushort_t* gb, ushort_t* la, ushort_t* lb,
    const ushort_t* sA, const ushort_t* sB,
    float4v (&acc)[4][4], int wm, int wn, int l15, int quad) {
  float4v a0[4], a1[4];
#pragma unroll
  for (int i = 0; i < 4; ++i) {
    a0[i] = *(const float4v*)(ga + i * 16384);
    a1[i] = *(const float4v*)(ga + i * 16384 + 4);
  }
#pragma unroll
  for (int kk = 0; kk < 512; kk += 64) {
    __syncthreads();
#pragma unroll
    for (int i = 0; i < 4; ++i) {
      short8 cv;
#pragma unroll
      for (int e = 0; e < 4; ++e) {
        cv[e]     = (short)f2bf(a0[i][e]);
        cv[e + 4] = (short)f2bf(a1[i][e]);
      }
      *(short8*)(la + i * 2048) = cv;
      gl_lds16(gb + i * 16384 + kk, lb + i * 2048);
    }
    __syncthreads();
    if (kk < 448) {   // prefetch next A chunk; overlaps MFMA below
#pragma unroll
      for (int i = 0; i < 4; ++i) {
        a0[i] = *(const float4v*)(ga + i * 16384 + kk + 64);
        a1[i] = *(const float4v*)(ga + i * 16384 + kk + 68);
      }
    }
#pragma unroll
    for (int k2 = 0; k2 < 64; k2 += 32) {
      short8 af[4], bfr[4];
#pragma unroll
      for (int i = 0; i < 4; ++i)
        af[i] = *(const short8*)&sA[(wm + i * 16 + l15) * 64 + k2 + quad * 8];
#pragma unroll
      for (int j = 0; j < 4; ++j)
        bfr[j] = *(const short8*)&sB[(wn + j * 16 + l15) * 64 + k2 + quad * 8];
#pragma unroll
      for (int i = 0; i < 4; ++i)
#pragma unroll
        for (int j = 0; j < 4; ++j) {
          if constexpr (SWAP)
            acc[i][j] = __builtin_amdgcn_mfma_f32_16x16x32_bf16(bfr[j], af[i], acc[i][j], 0, 0, 0);
          else
            acc[i][j] = __builtin_amdgcn_mfma_f32_16x16x32_bf16(af[i], bfr[j], acc[i][j], 0, 0, 0);
        }
    }
  }
}

// QKV: x[32768x512]f32 @ Wqkv[1536x512]^T. 3072 blocks, XCD-swizzled.
__global__ __launch_bounds__(256) void qkv_kernel(
    const float* __restrict__ x, const ushort_t* __restrict__ Wb,
    ushort_t* __restrict__ q_ws, ushort_t* __restrict__ k_ws,
    ushort_t* __restrict__ v_tok, float* __restrict__ normsSq) {
  // swizzle: XCD = blk&7 owns 32 contiguous m-rows x all 12 n-cols (A set = 4MB = L2)
  const int l = blockIdx.x;
  const int xcd = l & 7, lx = l >> 3;
  const int col = lx % 12;
  const int mrow = xcd * 32 + lx / 12;
  const int n0 = col * 128, m0 = mrow * 128;

  __shared__ ushort_t sA[8192];
  __shared__ ushort_t sB[8192];

  const int tid = threadIdx.x;
  const int lr = tid >> 3, lc = (tid & 7) * 8;
  const float* ga = x + (size_t)(m0 + lr) * 512 + lc;
  const ushort_t* gb = Wb + (size_t)(n0 + lr) * 512 + lc;
  ushort_t* la = &sA[lr * 64 + lc];
  ushort_t* lb = &sB[lr * 64 + lc];

  const int w = tid >> 6, lane = tid & 63, l15 = lane & 15, quad = lane >> 4;
  const int wm = (w >> 1) * 64, wn = (w & 1) * 64;

  float4v acc[4][4];
#pragma unroll
  for (int i = 0; i < 4; ++i)
#pragma unroll
    for (int j = 0; j < 4; ++j) acc[i][j] = (float4v){0.f, 0.f, 0.f, 0.f};

  const bool isV = (n0 >= 1024);
  if (isV) qkv_kloop<true>(ga, gb, la, lb, sA, sB, acc, wm, wn, l15, quad);
  else     qkv_kloop<false>(ga, gb, la, lb, sA, sB, acc, wm, wn, l15, quad);

  const int b = m0 >> 13;
  if (isV) {
    // D rows = channel (quad*4+rg), cols = token (l15). 16 x 8B stores.
    const int chBase = n0 - 1024;
#pragma unroll
    for (int i = 0; i < 4; ++i) {
      int tok = m0 + wm + i * 16 + l15;
      int n = tok & 8191;
      ushort_t* dst = v_tok + ((size_t)b * 8192 + n) * 512 + chBase + wn + quad * 4;
#pragma unroll
      for (int j = 0; j < 4; ++j) {
        ushort4v pk;
#pragma unroll
        for (int rg = 0; rg < 4; ++rg) pk[rg] = f2bf(acc[i][j][rg]);
        *(ushort4v*)(dst + j * 16) = pk;
      }
    }
  } else {
    const int t3 = n0 >> 9;              // 0=q 1=k
    const int h = (n0 >> 7) & 3;
    const int bh = b * 4 + h;
    ushort_t* dstT = t3 ? k_ws : q_ws;
    float* nrm = normsSq + (t3 ? 2048 : 0) + bh * 128;
#pragma unroll
    for (int j = 0; j < 4; ++j) {
      int c = wn + j * 16 + l15;
      float s = 0.f;
#pragma unroll
      for (int i = 0; i < 4; ++i) {
        int n = (m0 + wm + i * 16 + quad * 4) & 8191;
        ushort4v pk;
#pragma unroll
        for (int rg = 0; rg < 4; ++rg) {
          float v = acc[i][j][rg];
          pk[rg] = f2bf(v);
          s += v * v;
        }
        *(ushort4v*)(dstT + ((size_t)bh * 128 + c) * 8192 + n) = pk;
      }
      s += __shfl_xor(s, 16);
      s += __shfl_xor(s, 32);
      if (quad == 0) atomicAdd(nrm + c, s);
    }
  }
}

// Generic 128x128 GEMM (bf16 ws operands, gl_lds staging), compile-time K.
// MODE 1: S split-K partials; MODE 2: W2; MODE 3: OUT (1D swizzled grid, +bias).
template <int MODE>
__global__ __launch_bounds__(256) void gemm128(
    const ushort_t* __restrict__ A, const ushort_t* __restrict__ B,
    float* __restrict__ outF, ushort_t* __restrict__ outU,
    const float* __restrict__ bias) {
  constexpr int K = (MODE == 2) ? 128 : 512;
  const int tid = threadIdx.x;
  int z, m0, n0, lda, ldb;
  const ushort_t *Ab, *Bb;
  if constexpr (MODE == 1) {
    z = blockIdx.z;
    int bh = z >> 4, s = z & 15;
    m0 = 0; n0 = 0; lda = 8192; ldb = 8192;
    Ab = A + (size_t)bh * 1048576 + s * 512;
    Bb = B + (size_t)bh * 1048576 + s * 512;
  } else if constexpr (MODE == 2) {
    z = blockIdx.z;
    m0 = blockIdx.y * 128; n0 = 0; lda = 512; ldb = 128;
    Ab = A + (z & 3) * 128;
    Bb = B + (size_t)z * 16384;
  } else {
    int l = blockIdx.x;
    int xcd = l & 7, lx = l >> 3;
    int colb = lx & 3;
    int mr = xcd * 32 + (lx >> 2);     // 0..255
    z = mr >> 6; m0 = (mr & 63) * 128; n0 = colb * 128;
    lda = 512; ldb = 512;
    Ab = A + (size_t)z * 8192 * 512;
    Bb = B + (size_t)z * 512 * 512;
  }

  __shared__ ushort_t sA[8192];
  __shared__ ushort_t sB[8192];

  const int lr = tid >> 3, lc = (tid & 7) * 8;
  const ushort_t* ga = Ab + (size_t)(m0 + lr) * lda + lc;
  const ushort_t* gb = Bb + (size_t)(n0 + lr) * ldb + lc;
  ushort_t* la = &sA[lr * 64 + lc];
  ushort_t* lb = &sB[lr * 64 + lc];

  const int w = tid >> 6, lane = tid & 63, l15 = lane & 15, quad = lane >> 4;
  const int wm = (w >> 1) * 64, wn = (w & 1) * 64;

  float4v acc[4][4];
#pragma unroll
  for (int i = 0; i < 4; ++i)
#pragma unroll
    for (int j = 0; j < 4; ++j) acc[i][j] = (float4v){0.f, 0.f, 0.f, 0.f};

#pragma unroll
  for (int kk = 0; kk < K; kk += 64) {
    __syncthreads();
#pragma unroll
    for (int i = 0; i < 4; ++i) {
      gl_lds16(ga + (size_t)i * 32 * lda + kk, la + i * 2048);
      gl_lds16(gb + (size_t)i * 32 * ldb + kk, lb + i * 2048);
    }
    __syncthreads();
#pragma unroll
    for (int k2 = 0; k2 < 64; k2 += 32) {
      short8 af[4], bfr[4];
#pragma unroll
      for (int i = 0; i < 4; ++i)
        af[i] = *(const short8*)&sA[(wm + i * 16 + l15) * 64 + k2 + quad * 8];
#pragma unroll
      for (int j = 0; j < 4; ++j)
        bfr[j] = *(const short8*)&sB[(wn + j * 16 + l15) * 64 + k2 + quad * 8];
#pragma unroll
      for (int i = 0; i < 4; ++i)
#pragma unroll
        for (int j = 0; j < 4; ++j)
          acc[i][j] = __builtin_amdgcn_mfma_f32_16x16x32_bf16(af[i], bfr[j], acc[i][j], 0, 0, 0);
    }
  }

  if constexpr (MODE == 1) {
#pragma unroll
    for (int i = 0; i < 4; ++i)
#pragma unroll
      for (int j = 0; j < 4; ++j)
#pragma unroll
        for (int rg = 0; rg < 4; ++rg)
          outF[(size_t)z * 16384 + (size_t)(wm + i * 16 + quad * 4 + rg) * 128 +
               wn + j * 16 + l15] = acc[i][j][rg];
  } else if constexpr (MODE == 2) {
    int b = z >> 2, h = z & 3;
#pragma unroll
    for (int i = 0; i < 4; ++i)
#pragma unroll
      for (int j = 0; j < 4; ++j)
#pragma unroll
        for (int rg = 0; rg < 4; ++rg)
          outU[((size_t)b * 512 + m0 + wm + i * 16 + quad * 4 + rg) * 512 +
               h * 128 + wn + j * 16 + l15] = f2bf(acc[i][j][rg]);
  } else {
#pragma unroll
    for (int i = 0; i < 4; ++i)
#pragma unroll
      for (int j = 0; j < 4; ++j) {
        int gcol = n0 + wn + j * 16 + l15;
        float bv = bias[gcol];
#pragma unroll
        for (int rg = 0; rg < 4; ++rg)
          outF[((size_t)z * 8192 + m0 + wm + i * 16 + quad * 4 + rg) * 512 + gcol] =
              acc[i][j][rg] + bv;
      }
  }
}

// Sum 16 split-K partials, normalize by sqrt(normsSq), temperature, softmax
// over d, write attn TRANSPOSED attn_t[bh][d][c]. grid (128,16) x 64.
__global__ void attn_softmax(const float* __restrict__ Sp,
                             const float* __restrict__ normsSq,
                             const float* __restrict__ temp,
                             ushort_t* __restrict__ attn_t) {
  int c = blockIdx.x, bh = blockIdx.y, h = bh & 3;
  int lane = threadIdx.x;
  const float* base = Sp + (size_t)bh * 16 * 16384 + (size_t)c * 128;
  float v0 = 0.f, v1 = 0.f;
#pragma unroll
  for (int s = 0; s < 16; ++s) {
    v0 += base[s * 16384 + lane];
    v1 += base[s * 16384 + lane + 64];
  }
  float nq = fmaxf(sqrtf(normsSq[bh * 128 + c]), 1e-12f);
  float sc = temp[h] / nq;
  v0 = v0 * sc / fmaxf(sqrtf(normsSq[2048 + bh * 128 + lane]), 1e-12f);
  v1 = v1 * sc / fmaxf(sqrtf(normsSq[2048 + bh * 128 + lane + 64]), 1e-12f);
  float m = fmaxf(v0, v1);
#pragma unroll
  for (int off = 32; off; off >>= 1) m = fmaxf(m, __shfl_xor(m, off));
  float e0 = expf(v0 - m), e1 = expf(v1 - m);
  float s = e0 + e1;
#pragma unroll
  for (int off = 32; off; off >>= 1) s += __shfl_xor(s, off);
  float inv = 1.0f / s;
  attn_t[(size_t)bh * 16384 + (size_t)lane * 128 + c] = f2bf(e0 * inv);
  attn_t[(size_t)bh * 16384 + (size_t)(lane + 64) * 128 + c] = f2bf(e1 * inv);
}

extern "C" void kernel_launch(void* const* d_in, const int* in_sizes, int n_in,
                              void* d_out, int out_size, void* d_ws, size_t ws_size,
                              hipStream_t stream) {
  const float* x    = (const float*)d_in[0];   // [4,8192,512]
  const float* Wqkv = (const float*)d_in[1];   // [1536,512]
  const float* Wout = (const float*)d_in[2];   // [512,512]
  const float* bout = (const float*)d_in[3];   // [512]
  const float* temp = (const float*)d_in[4];   // [4,1,1]
  float* out = (float*)d_out;                  // [4,8192,512] f32

  char* ws = (char*)d_ws;
  float*    S_par   = (float*)(ws);                  // 16,777,216 B
  float*    normsSq = (float*)(ws + 16777216);       //     16,384 B
  ushort_t* attnT   = (ushort_t*)(ws + 16793600);    //    524,288 B
  ushort_t* W2b     = (ushort_t*)(ws + 17317888);    //  2,097,152 B
  ushort_t* q_ws    = (ushort_t*)(ws + 33554432);    // 33,554,432 B [bh][c][n]
  ushort_t* k_ws    = (ushort_t*)(ws + 67108864);    // 33,554,432 B
  ushort_t* v_tok   = (ushort_t*)(ws + 100663296);   // 33,554,432 B [b][n][ch]
  ushort_t* Wqkvb   = (ushort_t*)(ws + 134217728);   //  1,572,864 B
  ushort_t* Woutb   = (ushort_t*)(ws + 135790592);   //    524,288 B

  hipMemsetAsync(normsSq, 0, 16384, stream);

  convert_w<<<dim3(1024), dim3(256), 0, stream>>>(Wqkv, Wout, Wqkvb, Woutb);

  qkv_kernel<<<dim3(3072), dim3(256), 0, stream>>>(
      x, Wqkvb, q_ws, k_ws, v_tok, normsSq);

  gemm128<1><<<dim3(1, 1, 256), dim3(256), 0, stream>>>(
      q_ws, k_ws, S_par, nullptr, nullptr);

  attn_softmax<<<dim3(128, 16), dim3(64), 0, stream>>>(S_par, normsSq, temp, attnT);

  gemm128<2><<<dim3(1, 4, 16), dim3(256), 0, stream>>>(
      Woutb, attnT, nullptr, W2b, nullptr);

  gemm128<3><<<dim3(1024), dim3(256), 0, stream>>>(
      v_tok, W2b, out, nullptr, bout);
}

// Round 5
// 271.487 us; speedup vs baseline: 1.2240x; 1.2240x over previous
//
#include <hip/hip_runtime.h>

// ChannelAttention (XCA): B=4, N=8192, C=512, heads=4, dh=128. FP32 in/out.
// R5: QKV reverted to dual gl_lds staging (pre-converted bf16 x) — R4's fused
//     fp32 staging serialized two latency waits per K-iter (173us vs 103us).
//     Kept: XCD swizzle (FETCH 137->56MB), v operand-swap epilogue, fused
//     norms atomics, S split-K=16. normsSq zeroing folded into convert.

typedef unsigned short ushort_t;
typedef __attribute__((ext_vector_type(8))) short short8;
typedef __attribute__((ext_vector_type(4))) float float4v;
typedef __attribute__((ext_vector_type(4))) unsigned short ushort4v;

__device__ __forceinline__ ushort_t f2bf(float f) {
  union { float f; unsigned u; } c; c.f = f;
  unsigned u = c.u;
  u += 0x7fffu + ((u >> 16) & 1u);   // RNE
  return (ushort_t)(u >> 16);
}

typedef const __attribute__((address_space(1))) unsigned int guint_t;
typedef __attribute__((address_space(3))) unsigned int luint_t;
__device__ __forceinline__ void gl_lds16(const ushort_t* g, ushort_t* l) {
  __builtin_amdgcn_global_load_lds((guint_t*)g, (luint_t*)l, 16, 0, 0);
}

// fp32->bf16: x (4194304 groups of 4), Wqkv (196608), Wout (65536); also
// zeroes normsSq (4096 floats) so QKV epilogue atomics start from 0.
__global__ __launch_bounds__(256) void convert_bf16(
    const float* __restrict__ x, const float* __restrict__ w1,
    const float* __restrict__ w2, ushort_t* __restrict__ xb,
    ushort_t* __restrict__ w1b, ushort_t* __restrict__ w2b,
    float* __restrict__ normsSq) {
  int g = blockIdx.x * 256 + threadIdx.x;
  if (g < 1024) *(float4v*)(normsSq + g * 4) = (float4v){0.f, 0.f, 0.f, 0.f};
  const float* src; ushort_t* dst; int off;
  if (g < 4194304)      { src = x;  dst = xb;  off = g; }
  else if (g < 4390912) { src = w1; dst = w1b; off = g - 4194304; }
  else                  { src = w2; dst = w2b; off = g - 4390912; }
  size_t e = (size_t)off * 4;
  float4v f = *(const float4v*)(src + e);
  ushort4v o;
#pragma unroll
  for (int i = 0; i < 4; ++i) o[i] = f2bf(f[i]);
  *(ushort4v*)(dst + e) = o;
}

// K-loop: both operands bf16 via gl_lds (one latency wait per iter).
// SWAP=true computes D = B.A (v blocks: D rows=channel, cols=token).
template <bool SWAP>
__device__ __forceinline__ void kloop512(
    const ushort_t* ga, const ushort_t* gb, ushort_t* la, ushort_t* lb,
    const ushort_t* sA, const ushort_t* sB,
    float4v (&acc)[4][4], int wm, int wn, int l15, int quad) {
#pragma unroll
  for (int kk = 0; kk < 512; kk += 64) {
    __syncthreads();
#pragma unroll
    for (int i = 0; i < 4; ++i) {
      gl_lds16(ga + i * 16384 + kk, la + i * 2048);
      gl_lds16(gb + i * 16384 + kk, lb + i * 2048);
    }
    __syncthreads();
#pragma unroll
    for (int k2 = 0; k2 < 64; k2 += 32) {
      short8 af[4], bfr[4];
#pragma unroll
      for (int i = 0; i < 4; ++i)
        af[i] = *(const short8*)&sA[(wm + i * 16 + l15) * 64 + k2 + quad * 8];
#pragma unroll
      for (int j = 0; j < 4; ++j)
        bfr[j] = *(const short8*)&sB[(wn + j * 16 + l15) * 64 + k2 + quad * 8];
#pragma unroll
      for (int i = 0; i < 4; ++i)
#pragma unroll
        for (int j = 0; j < 4; ++j) {
          if constexpr (SWAP)
            acc[i][j] = __builtin_amdgcn_mfma_f32_16x16x32_bf16(bfr[j], af[i], acc[i][j], 0, 0, 0);
          else
            acc[i][j] = __builtin_amdgcn_mfma_f32_16x16x32_bf16(af[i], bfr[j], acc[i][j], 0, 0, 0);
        }
    }
  }
}

// QKV: x_bf[32768x512] @ Wqkv_bf[1536x512]^T. 3072 blocks, XCD-swizzled:
// XCD = blk&7 owns 32 contiguous m-panels x all 12 n-cols (A set = 4MB = L2).
__global__ __launch_bounds__(256) void qkv_kernel(
    const ushort_t* __restrict__ xb, const ushort_t* __restrict__ Wb,
    ushort_t* __restrict__ q_ws, ushort_t* __restrict__ k_ws,
    ushort_t* __restrict__ v_tok, float* __restrict__ normsSq) {
  const int l = blockIdx.x;
  const int xcd = l & 7, lx = l >> 3;
  const int col = lx % 12;
  const int mrow = xcd * 32 + lx / 12;
  const int n0 = col * 128, m0 = mrow * 128;

  __shared__ ushort_t sA[8192];
  __shared__ ushort_t sB[8192];

  const int tid = threadIdx.x;
  const int lr = tid >> 3, lc = (tid & 7) * 8;
  const ushort_t* ga = xb + (size_t)(m0 + lr) * 512 + lc;
  const ushort_t* gb = Wb + (size_t)(n0 + lr) * 512 + lc;
  ushort_t* la = &sA[lr * 64 + lc];
  ushort_t* lb = &sB[lr * 64 + lc];

  const int w = tid >> 6, lane = tid & 63, l15 = lane & 15, quad = lane >> 4;
  const int wm = (w >> 1) * 64, wn = (w & 1) * 64;

  float4v acc[4][4];
#pragma unroll
  for (int i = 0; i < 4; ++i)
#pragma unroll
    for (int j = 0; j < 4; ++j) acc[i][j] = (float4v){0.f, 0.f, 0.f, 0.f};

  const bool isV = (n0 >= 1024);
  if (isV) kloop512<true>(ga, gb, la, lb, sA, sB, acc, wm, wn, l15, quad);
  else     kloop512<false>(ga, gb, la, lb, sA, sB, acc, wm, wn, l15, quad);

  const int b = m0 >> 13;
  if (isV) {
    // D rows = channel (quad*4+rg), cols = token (l15). 16 x 8B stores.
    const int chBase = n0 - 1024;
#pragma unroll
    for (int i = 0; i < 4; ++i) {
      int n = (m0 + wm + i * 16 + l15) & 8191;
      ushort_t* dst = v_tok + ((size_t)b * 8192 + n) * 512 + chBase + wn + quad * 4;
#pragma unroll
      for (int j = 0; j < 4; ++j) {
        ushort4v pk;
#pragma unroll
        for (int rg = 0; rg < 4; ++rg) pk[rg] = f2bf(acc[i][j][rg]);
        *(ushort4v*)(dst + j * 16) = pk;
      }
    }
  } else {
    const int t3 = n0 >> 9;              // 0=q 1=k
    const int h = (n0 >> 7) & 3;
    const int bh = b * 4 + h;
    ushort_t* dstT = t3 ? k_ws : q_ws;
    float* nrm = normsSq + (t3 ? 2048 : 0) + bh * 128;
#pragma unroll
    for (int j = 0; j < 4; ++j) {
      int c = wn + j * 16 + l15;
      float s = 0.f;
#pragma unroll
      for (int i = 0; i < 4; ++i) {
        int n = (m0 + wm + i * 16 + quad * 4) & 8191;
        ushort4v pk;
#pragma unroll
        for (int rg = 0; rg < 4; ++rg) {
          float v = acc[i][j][rg];
          pk[rg] = f2bf(v);
          s += v * v;
        }
        *(ushort4v*)(dstT + ((size_t)bh * 128 + c) * 8192 + n) = pk;
      }
      s += __shfl_xor(s, 16);
      s += __shfl_xor(s, 32);
      if (quad == 0) atomicAdd(nrm + c, s);
    }
  }
}

// Generic 128x128 GEMM (bf16 operands, gl_lds staging), compile-time K.
// MODE 1: S split-K=16 partials; MODE 2: W2; MODE 3: OUT (swizzled, +bias).
template <int MODE>
__global__ __launch_bounds__(256) void gemm128(
    const ushort_t* __restrict__ A, const ushort_t* __restrict__ B,
    float* __restrict__ outF, ushort_t* __restrict__ outU,
    const float* __restrict__ bias) {
  constexpr int K = (MODE == 2) ? 128 : 512;
  const int tid = threadIdx.x;
  int z, m0, n0, lda, ldb;
  const ushort_t *Ab, *Bb;
  if constexpr (MODE == 1) {
    z = blockIdx.z;
    int bh = z >> 4, s = z & 15;
    m0 = 0; n0 = 0; lda = 8192; ldb = 8192;
    Ab = A + (size_t)bh * 1048576 + s * 512;
    Bb = B + (size_t)bh * 1048576 + s * 512;
  } else if constexpr (MODE == 2) {
    z = blockIdx.z;
    m0 = blockIdx.y * 128; n0 = 0; lda = 512; ldb = 128;
    Ab = A + (z & 3) * 128;
    Bb = B + (size_t)z * 16384;
  } else {
    int l = blockIdx.x;
    int xcd = l & 7, lx = l >> 3;
    int colb = lx & 3;
    int mr = xcd * 32 + (lx >> 2);     // 0..255
    z = mr >> 6; m0 = (mr & 63) * 128; n0 = colb * 128;
    lda = 512; ldb = 512;
    Ab = A + (size_t)z * 8192 * 512;
    Bb = B + (size_t)z * 512 * 512;
  }

  __shared__ ushort_t sA[8192];
  __shared__ ushort_t sB[8192];

  const int lr = tid >> 3, lc = (tid & 7) * 8;
  const ushort_t* ga = Ab + (size_t)(m0 + lr) * lda + lc;
  const ushort_t* gb = Bb + (size_t)(n0 + lr) * ldb + lc;
  ushort_t* la = &sA[lr * 64 + lc];
  ushort_t* lb = &sB[lr * 64 + lc];

  const int w = tid >> 6, lane = tid & 63, l15 = lane & 15, quad = lane >> 4;
  const int wm = (w >> 1) * 64, wn = (w & 1) * 64;

  float4v acc[4][4];
#pragma unroll
  for (int i = 0; i < 4; ++i)
#pragma unroll
    for (int j = 0; j < 4; ++j) acc[i][j] = (float4v){0.f, 0.f, 0.f, 0.f};

#pragma unroll
  for (int kk = 0; kk < K; kk += 64) {
    __syncthreads();
#pragma unroll
    for (int i = 0; i < 4; ++i) {
      gl_lds16(ga + (size_t)i * 32 * lda + kk, la + i * 2048);
      gl_lds16(gb + (size_t)i * 32 * ldb + kk, lb + i * 2048);
    }
    __syncthreads();
#pragma unroll
    for (int k2 = 0; k2 < 64; k2 += 32) {
      short8 af[4], bfr[4];
#pragma unroll
      for (int i = 0; i < 4; ++i)
        af[i] = *(const short8*)&sA[(wm + i * 16 + l15) * 64 + k2 + quad * 8];
#pragma unroll
      for (int j = 0; j < 4; ++j)
        bfr[j] = *(const short8*)&sB[(wn + j * 16 + l15) * 64 + k2 + quad * 8];
#pragma unroll
      for (int i = 0; i < 4; ++i)
#pragma unroll
        for (int j = 0; j < 4; ++j)
          acc[i][j] = __builtin_amdgcn_mfma_f32_16x16x32_bf16(af[i], bfr[j], acc[i][j], 0, 0, 0);
    }
  }

  if constexpr (MODE == 1) {
#pragma unroll
    for (int i = 0; i < 4; ++i)
#pragma unroll
      for (int j = 0; j < 4; ++j)
#pragma unroll
        for (int rg = 0; rg < 4; ++rg)
          outF[(size_t)z * 16384 + (size_t)(wm + i * 16 + quad * 4 + rg) * 128 +
               wn + j * 16 + l15] = acc[i][j][rg];
  } else if constexpr (MODE == 2) {
    int b = z >> 2, h = z & 3;
#pragma unroll
    for (int i = 0; i < 4; ++i)
#pragma unroll
      for (int j = 0; j < 4; ++j)
#pragma unroll
        for (int rg = 0; rg < 4; ++rg)
          outU[((size_t)b * 512 + m0 + wm + i * 16 + quad * 4 + rg) * 512 +
               h * 128 + wn + j * 16 + l15] = f2bf(acc[i][j][rg]);
  } else {
#pragma unroll
    for (int i = 0; i < 4; ++i)
#pragma unroll
      for (int j = 0; j < 4; ++j) {
        int gcol = n0 + wn + j * 16 + l15;
        float bv = bias[gcol];
#pragma unroll
        for (int rg = 0; rg < 4; ++rg)
          outF[((size_t)z * 8192 + m0 + wm + i * 16 + quad * 4 + rg) * 512 + gcol] =
              acc[i][j][rg] + bv;
      }
  }
}

// Sum 16 split-K partials, normalize by sqrt(normsSq), temperature, softmax
// over d, write attn TRANSPOSED attn_t[bh][d][c]. grid (128,16) x 64.
__global__ void attn_softmax(const float* __restrict__ Sp,
                             const float* __restrict__ normsSq,
                             const float* __restrict__ temp,
                             ushort_t* __restrict__ attn_t) {
  int c = blockIdx.x, bh = blockIdx.y, h = bh & 3;
  int lane = threadIdx.x;
  const float* base = Sp + (size_t)bh * 16 * 16384 + (size_t)c * 128;
  float v0 = 0.f, v1 = 0.f;
#pragma unroll
  for (int s = 0; s < 16; ++s) {
    v0 += base[s * 16384 + lane];
    v1 += base[s * 16384 + lane + 64];
  }
  float nq = fmaxf(sqrtf(normsSq[bh * 128 + c]), 1e-12f);
  float sc = temp[h] / nq;
  v0 = v0 * sc / fmaxf(sqrtf(normsSq[2048 + bh * 128 + lane]), 1e-12f);
  v1 = v1 * sc / fmaxf(sqrtf(normsSq[2048 + bh * 128 + lane + 64]), 1e-12f);
  float m = fmaxf(v0, v1);
#pragma unroll
  for (int off = 32; off; off >>= 1) m = fmaxf(m, __shfl_xor(m, off));
  float e0 = expf(v0 - m), e1 = expf(v1 - m);
  float s = e0 + e1;
#pragma unroll
  for (int off = 32; off; off >>= 1) s += __shfl_xor(s, off);
  float inv = 1.0f / s;
  attn_t[(size_t)bh * 16384 + (size_t)lane * 128 + c] = f2bf(e0 * inv);
  attn_t[(size_t)bh * 16384 + (size_t)(lane + 64) * 128 + c] = f2bf(e1 * inv);
}

extern "C" void kernel_launch(void* const* d_in, const int* in_sizes, int n_in,
                              void* d_out, int out_size, void* d_ws, size_t ws_size,
                              hipStream_t stream) {
  const float* x    = (const float*)d_in[0];   // [4,8192,512]
  const float* Wqkv = (const float*)d_in[1];   // [1536,512]
  const float* Wout = (const float*)d_in[2];   // [512,512]
  const float* bout = (const float*)d_in[3];   // [512]
  const float* temp = (const float*)d_in[4];   // [4,1,1]
  float* out = (float*)d_out;                  // [4,8192,512] f32

  char* ws = (char*)d_ws;
  // Region A (0..33.5MB): x_bf during QKV; reused afterwards by S_par/attnT/W2b.
  ushort_t* x_bf    = (ushort_t*)(ws);               // 33,554,432 B
  float*    S_par   = (float*)(ws);                  // 16,777,216 B (post-QKV)
  ushort_t* attnT   = (ushort_t*)(ws + 16777216);    //    524,288 B
  ushort_t* W2b     = (ushort_t*)(ws + 17301504);    //  2,097,152 B
  ushort_t* q_ws    = (ushort_t*)(ws + 33554432);    // 33,554,432 B [bh][c][n]
  ushort_t* k_ws    = (ushort_t*)(ws + 67108864);    // 33,554,432 B
  ushort_t* v_tok   = (ushort_t*)(ws + 100663296);   // 33,554,432 B [b][n][ch]
  ushort_t* Wqkvb   = (ushort_t*)(ws + 134217728);   //  1,572,864 B
  ushort_t* Woutb   = (ushort_t*)(ws + 135790592);   //    524,288 B
  float*    normsSq = (float*)(ws + 136314880);      //     16,384 B (live during QKV)

  convert_bf16<<<dim3(17408), dim3(256), 0, stream>>>(
      x, Wqkv, Wout, x_bf, Wqkvb, Woutb, normsSq);

  qkv_kernel<<<dim3(3072), dim3(256), 0, stream>>>(
      x_bf, Wqkvb, q_ws, k_ws, v_tok, normsSq);

  gemm128<1><<<dim3(1, 1, 256), dim3(256), 0, stream>>>(
      q_ws, k_ws, S_par, nullptr, nullptr);

  attn_softmax<<<dim3(128, 16), dim3(64), 0, stream>>>(S_par, normsSq, temp, attnT);

  gemm128<2><<<dim3(1, 4, 16), dim3(256), 0, stream>>>(
      Woutb, attnT, nullptr, W2b, nullptr);

  gemm128<3><<<dim3(1024), dim3(256), 0, stream>>>(
      v_tok, W2b, out, nullptr, bout);
}

// Round 6
// 256.076 us; speedup vs baseline: 1.2977x; 1.0602x over previous
//
#include <hip/hip_runtime.h>

// ChannelAttention (XCA): B=4, N=8192, C=512, heads=4, dh=128. FP32 in/out.
// R6: XOR-swizzled LDS chunk layout (slot = chunk ^ (row&7)) kills the 8-way
//     bank conflict on fragment ds_read_b128 (SQ_LDS_BANK_CONFLICT 1.9e7).
//     Staging lane->global-chunk permuted to match; gl_lds dest unchanged
//     (wave-uniform base + lane*16). Everything else as R5.

typedef unsigned short ushort_t;
typedef __attribute__((ext_vector_type(8))) short short8;
typedef __attribute__((ext_vector_type(4))) float float4v;
typedef __attribute__((ext_vector_type(4))) unsigned short ushort4v;

__device__ __forceinline__ ushort_t f2bf(float f) {
  union { float f; unsigned u; } c; c.f = f;
  unsigned u = c.u;
  u += 0x7fffu + ((u >> 16) & 1u);   // RNE
  return (ushort_t)(u >> 16);
}

typedef const __attribute__((address_space(1))) unsigned int guint_t;
typedef __attribute__((address_space(3))) unsigned int luint_t;
__device__ __forceinline__ void gl_lds16(const ushort_t* g, ushort_t* l) {
  __builtin_amdgcn_global_load_lds((guint_t*)g, (luint_t*)l, 16, 0, 0);
}

// fp32->bf16: x (4194304 groups of 4), Wqkv (196608), Wout (65536); also
// zeroes normsSq (4096 floats) so QKV epilogue atomics start from 0.
__global__ __launch_bounds__(256) void convert_bf16(
    const float* __restrict__ x, const float* __restrict__ w1,
    const float* __restrict__ w2, ushort_t* __restrict__ xb,
    ushort_t* __restrict__ w1b, ushort_t* __restrict__ w2b,
    float* __restrict__ normsSq) {
  int g = blockIdx.x * 256 + threadIdx.x;
  if (g < 1024) *(float4v*)(normsSq + g * 4) = (float4v){0.f, 0.f, 0.f, 0.f};
  const float* src; ushort_t* dst; int off;
  if (g < 4194304)      { src = x;  dst = xb;  off = g; }
  else if (g < 4390912) { src = w1; dst = w1b; off = g - 4194304; }
  else                  { src = w2; dst = w2b; off = g - 4390912; }
  size_t e = (size_t)off * 4;
  float4v f = *(const float4v*)(src + e);
  ushort4v o;
#pragma unroll
  for (int i = 0; i < 4; ++i) o[i] = f2bf(f[i]);
  *(ushort4v*)(dst + e) = o;
}

// Fragment read with XOR-swizzled slot: LDS slot (r, c) holds global chunk
// c ^ (r&7). For rows wm+i*16+l15 the key is l15&7 (wm,i*16 are mult of 8).
__device__ __forceinline__ short8 frag_read(const ushort_t* s, int row, int g, int xk) {
  return *(const short8*)&s[row * 64 + ((g ^ xk) << 3)];
}

// K-loop: both operands bf16 via gl_lds (one latency wait per iter).
// SWAP=true computes D = B.A (v blocks: D rows=channel, cols=token).
template <bool SWAP>
__device__ __forceinline__ void kloop512(
    const ushort_t* ga, const ushort_t* gb, ushort_t* la, ushort_t* lb,
    const ushort_t* sA, const ushort_t* sB,
    float4v (&acc)[4][4], int wm, int wn, int l15, int quad) {
  const int xk = l15 & 7;
#pragma unroll
  for (int kk = 0; kk < 512; kk += 64) {
    __syncthreads();
#pragma unroll
    for (int i = 0; i < 4; ++i) {
      gl_lds16(ga + i * 16384 + kk, la + i * 2048);
      gl_lds16(gb + i * 16384 + kk, lb + i * 2048);
    }
    __syncthreads();
#pragma unroll
    for (int k2 = 0; k2 < 64; k2 += 32) {
      const int g = (k2 >> 3) + quad;
      short8 af[4], bfr[4];
#pragma unroll
      for (int i = 0; i < 4; ++i)
        af[i] = frag_read(sA, wm + i * 16 + l15, g, xk);
#pragma unroll
      for (int j = 0; j < 4; ++j)
        bfr[j] = frag_read(sB, wn + j * 16 + l15, g, xk);
#pragma unroll
      for (int i = 0; i < 4; ++i)
#pragma unroll
        for (int j = 0; j < 4; ++j) {
          if constexpr (SWAP)
            acc[i][j] = __builtin_amdgcn_mfma_f32_16x16x32_bf16(bfr[j], af[i], acc[i][j], 0, 0, 0);
          else
            acc[i][j] = __builtin_amdgcn_mfma_f32_16x16x32_bf16(af[i], bfr[j], acc[i][j], 0, 0, 0);
        }
    }
  }
}

// QKV: x_bf[32768x512] @ Wqkv_bf[1536x512]^T. 3072 blocks, XCD-swizzled:
// XCD = blk&7 owns 32 contiguous m-panels x all 12 n-cols (A set = 4MB = L2).
__global__ __launch_bounds__(256) void qkv_kernel(
    const ushort_t* __restrict__ xb, const ushort_t* __restrict__ Wb,
    ushort_t* __restrict__ q_ws, ushort_t* __restrict__ k_ws,
    ushort_t* __restrict__ v_tok, float* __restrict__ normsSq) {
  const int l = blockIdx.x;
  const int xcd = l & 7, lx = l >> 3;
  const int col = lx % 12;
  const int mrow = xcd * 32 + lx / 12;
  const int n0 = col * 128, m0 = mrow * 128;

  __shared__ ushort_t sA[8192];
  __shared__ ushort_t sB[8192];

  const int tid = threadIdx.x;
  const int lr = tid >> 3, lcI = tid & 7;
  const int gc = lcI ^ (lr & 7);              // swizzle: lane loads chunk gc
  const ushort_t* ga = xb + (size_t)(m0 + lr) * 512 + gc * 8;
  const ushort_t* gb = Wb + (size_t)(n0 + lr) * 512 + gc * 8;
  ushort_t* la = &sA[lr * 64 + lcI * 8];      // = waveBase + lane*16B
  ushort_t* lb = &sB[lr * 64 + lcI * 8];

  const int w = tid >> 6, lane = tid & 63, l15 = lane & 15, quad = lane >> 4;
  const int wm = (w >> 1) * 64, wn = (w & 1) * 64;

  float4v acc[4][4];
#pragma unroll
  for (int i = 0; i < 4; ++i)
#pragma unroll
    for (int j = 0; j < 4; ++j) acc[i][j] = (float4v){0.f, 0.f, 0.f, 0.f};

  const bool isV = (n0 >= 1024);
  if (isV) kloop512<true>(ga, gb, la, lb, sA, sB, acc, wm, wn, l15, quad);
  else     kloop512<false>(ga, gb, la, lb, sA, sB, acc, wm, wn, l15, quad);

  const int b = m0 >> 13;
  if (isV) {
    // D rows = channel (quad*4+rg), cols = token (l15). 16 x 8B stores.
    const int chBase = n0 - 1024;
#pragma unroll
    for (int i = 0; i < 4; ++i) {
      int n = (m0 + wm + i * 16 + l15) & 8191;
      ushort_t* dst = v_tok + ((size_t)b * 8192 + n) * 512 + chBase + wn + quad * 4;
#pragma unroll
      for (int j = 0; j < 4; ++j) {
        ushort4v pk;
#pragma unroll
        for (int rg = 0; rg < 4; ++rg) pk[rg] = f2bf(acc[i][j][rg]);
        *(ushort4v*)(dst + j * 16) = pk;
      }
    }
  } else {
    const int t3 = n0 >> 9;              // 0=q 1=k
    const int h = (n0 >> 7) & 3;
    const int bh = b * 4 + h;
    ushort_t* dstT = t3 ? k_ws : q_ws;
    float* nrm = normsSq + (t3 ? 2048 : 0) + bh * 128;
#pragma unroll
    for (int j = 0; j < 4; ++j) {
      int c = wn + j * 16 + l15;
      float s = 0.f;
#pragma unroll
      for (int i = 0; i < 4; ++i) {
        int n = (m0 + wm + i * 16 + quad * 4) & 8191;
        ushort4v pk;
#pragma unroll
        for (int rg = 0; rg < 4; ++rg) {
          float v = acc[i][j][rg];
          pk[rg] = f2bf(v);
          s += v * v;
        }
        *(ushort4v*)(dstT + ((size_t)bh * 128 + c) * 8192 + n) = pk;
      }
      s += __shfl_xor(s, 16);
      s += __shfl_xor(s, 32);
      if (quad == 0) atomicAdd(nrm + c, s);
    }
  }
}

// Generic 128x128 GEMM (bf16 operands, gl_lds staging), compile-time K.
// MODE 1: S split-K=16 partials; MODE 2: W2; MODE 3: OUT (swizzled, +bias).
template <int MODE>
__global__ __launch_bounds__(256) void gemm128(
    const ushort_t* __restrict__ A, const ushort_t* __restrict__ B,
    float* __restrict__ outF, ushort_t* __restrict__ outU,
    const float* __restrict__ bias) {
  constexpr int K = (MODE == 2) ? 128 : 512;
  const int tid = threadIdx.x;
  int z, m0, n0, lda, ldb;
  const ushort_t *Ab, *Bb;
  if constexpr (MODE == 1) {
    z = blockIdx.z;
    int bh = z >> 4, s = z & 15;
    m0 = 0; n0 = 0; lda = 8192; ldb = 8192;
    Ab = A + (size_t)bh * 1048576 + s * 512;
    Bb = B + (size_t)bh * 1048576 + s * 512;
  } else if constexpr (MODE == 2) {
    z = blockIdx.z;
    m0 = blockIdx.y * 128; n0 = 0; lda = 512; ldb = 128;
    Ab = A + (z & 3) * 128;
    Bb = B + (size_t)z * 16384;
  } else {
    int l = blockIdx.x;
    int xcd = l & 7, lx = l >> 3;
    int colb = lx & 3;
    int mr = xcd * 32 + (lx >> 2);     // 0..255
    z = mr >> 6; m0 = (mr & 63) * 128; n0 = colb * 128;
    lda = 512; ldb = 512;
    Ab = A + (size_t)z * 8192 * 512;
    Bb = B + (size_t)z * 512 * 512;
  }

  __shared__ ushort_t sA[8192];
  __shared__ ushort_t sB[8192];

  const int lr = tid >> 3, lcI = tid & 7;
  const int gc = lcI ^ (lr & 7);
  const ushort_t* ga = Ab + (size_t)(m0 + lr) * lda + gc * 8;
  const ushort_t* gb = Bb + (size_t)(n0 + lr) * ldb + gc * 8;
  ushort_t* la = &sA[lr * 64 + lcI * 8];
  ushort_t* lb = &sB[lr * 64 + lcI * 8];

  const int w = tid >> 6, lane = tid & 63, l15 = lane & 15, quad = lane >> 4;
  const int wm = (w >> 1) * 64, wn = (w & 1) * 64;
  const int xk = l15 & 7;

  float4v acc[4][4];
#pragma unroll
  for (int i = 0; i < 4; ++i)
#pragma unroll
    for (int j = 0; j < 4; ++j) acc[i][j] = (float4v){0.f, 0.f, 0.f, 0.f};

#pragma unroll
  for (int kk = 0; kk < K; kk += 64) {
    __syncthreads();
#pragma unroll
    for (int i = 0; i < 4; ++i) {
      gl_lds16(ga + (size_t)i * 32 * lda + kk, la + i * 2048);
      gl_lds16(gb + (size_t)i * 32 * ldb + kk, lb + i * 2048);
    }
    __syncthreads();
#pragma unroll
    for (int k2 = 0; k2 < 64; k2 += 32) {
      const int g = (k2 >> 3) + quad;
      short8 af[4], bfr[4];
#pragma unroll
      for (int i = 0; i < 4; ++i)
        af[i] = frag_read(sA, wm + i * 16 + l15, g, xk);
#pragma unroll
      for (int j = 0; j < 4; ++j)
        bfr[j] = frag_read(sB, wn + j * 16 + l15, g, xk);
#pragma unroll
      for (int i = 0; i < 4; ++i)
#pragma unroll
        for (int j = 0; j < 4; ++j)
          acc[i][j] = __builtin_amdgcn_mfma_f32_16x16x32_bf16(af[i], bfr[j], acc[i][j], 0, 0, 0);
    }
  }

  if constexpr (MODE == 1) {
#pragma unroll
    for (int i = 0; i < 4; ++i)
#pragma unroll
      for (int j = 0; j < 4; ++j)
#pragma unroll
        for (int rg = 0; rg < 4; ++rg)
          outF[(size_t)z * 16384 + (size_t)(wm + i * 16 + quad * 4 + rg) * 128 +
               wn + j * 16 + l15] = acc[i][j][rg];
  } else if constexpr (MODE == 2) {
    int b = z >> 2, h = z & 3;
#pragma unroll
    for (int i = 0; i < 4; ++i)
#pragma unroll
      for (int j = 0; j < 4; ++j)
#pragma unroll
        for (int rg = 0; rg < 4; ++rg)
          outU[((size_t)b * 512 + m0 + wm + i * 16 + quad * 4 + rg) * 512 +
               h * 128 + wn + j * 16 + l15] = f2bf(acc[i][j][rg]);
  } else {
#pragma unroll
    for (int i = 0; i < 4; ++i)
#pragma unroll
      for (int j = 0; j < 4; ++j) {
        int gcol = n0 + wn + j * 16 + l15;
        float bv = bias[gcol];
#pragma unroll
        for (int rg = 0; rg < 4; ++rg)
          outF[((size_t)z * 8192 + m0 + wm + i * 16 + quad * 4 + rg) * 512 + gcol] =
              acc[i][j][rg] + bv;
      }
  }
}

// Sum 16 split-K partials, normalize by sqrt(normsSq), temperature, softmax
// over d, write attn TRANSPOSED attn_t[bh][d][c]. grid (128,16) x 64.
__global__ void attn_softmax(const float* __restrict__ Sp,
                             const float* __restrict__ normsSq,
                             const float* __restrict__ temp,
                             ushort_t* __restrict__ attn_t) {
  int c = blockIdx.x, bh = blockIdx.y, h = bh & 3;
  int lane = threadIdx.x;
  const float* base = Sp + (size_t)bh * 16 * 16384 + (size_t)c * 128;
  float v0 = 0.f, v1 = 0.f;
#pragma unroll
  for (int s = 0; s < 16; ++s) {
    v0 += base[s * 16384 + lane];
    v1 += base[s * 16384 + lane + 64];
  }
  float nq = fmaxf(sqrtf(normsSq[bh * 128 + c]), 1e-12f);
  float sc = temp[h] / nq;
  v0 = v0 * sc / fmaxf(sqrtf(normsSq[2048 + bh * 128 + lane]), 1e-12f);
  v1 = v1 * sc / fmaxf(sqrtf(normsSq[2048 + bh * 128 + lane + 64]), 1e-12f);
  float m = fmaxf(v0, v1);
#pragma unroll
  for (int off = 32; off; off >>= 1) m = fmaxf(m, __shfl_xor(m, off));
  float e0 = expf(v0 - m), e1 = expf(v1 - m);
  float s = e0 + e1;
#pragma unroll
  for (int off = 32; off; off >>= 1) s += __shfl_xor(s, off);
  float inv = 1.0f / s;
  attn_t[(size_t)bh * 16384 + (size_t)lane * 128 + c] = f2bf(e0 * inv);
  attn_t[(size_t)bh * 16384 + (size_t)(lane + 64) * 128 + c] = f2bf(e1 * inv);
}

extern "C" void kernel_launch(void* const* d_in, const int* in_sizes, int n_in,
                              void* d_out, int out_size, void* d_ws, size_t ws_size,
                              hipStream_t stream) {
  const float* x    = (const float*)d_in[0];   // [4,8192,512]
  const float* Wqkv = (const float*)d_in[1];   // [1536,512]
  const float* Wout = (const float*)d_in[2];   // [512,512]
  const float* bout = (const float*)d_in[3];   // [512]
  const float* temp = (const float*)d_in[4];   // [4,1,1]
  float* out = (float*)d_out;                  // [4,8192,512] f32

  char* ws = (char*)d_ws;
  // Region A (0..33.5MB): x_bf during QKV; reused afterwards by S_par/attnT/W2b.
  ushort_t* x_bf    = (ushort_t*)(ws);               // 33,554,432 B
  float*    S_par   = (float*)(ws);                  // 16,777,216 B (post-QKV)
  ushort_t* attnT   = (ushort_t*)(ws + 16777216);    //    524,288 B
  ushort_t* W2b     = (ushort_t*)(ws + 17301504);    //  2,097,152 B
  ushort_t* q_ws    = (ushort_t*)(ws + 33554432);    // 33,554,432 B [bh][c][n]
  ushort_t* k_ws    = (ushort_t*)(ws + 67108864);    // 33,554,432 B
  ushort_t* v_tok   = (ushort_t*)(ws + 100663296);   // 33,554,432 B [b][n][ch]
  ushort_t* Wqkvb   = (ushort_t*)(ws + 134217728);   //  1,572,864 B
  ushort_t* Woutb   = (ushort_t*)(ws + 135790592);   //    524,288 B
  float*    normsSq = (float*)(ws + 136314880);      //     16,384 B (live during QKV)

  convert_bf16<<<dim3(17408), dim3(256), 0, stream>>>(
      x, Wqkv, Wout, x_bf, Wqkvb, Woutb, normsSq);

  qkv_kernel<<<dim3(3072), dim3(256), 0, stream>>>(
      x_bf, Wqkvb, q_ws, k_ws, v_tok, normsSq);

  gemm128<1><<<dim3(1, 1, 256), dim3(256), 0, stream>>>(
      q_ws, k_ws, S_par, nullptr, nullptr);

  attn_softmax<<<dim3(128, 16), dim3(64), 0, stream>>>(S_par, normsSq, temp, attnT);

  gemm128<2><<<dim3(1, 4, 16), dim3(256), 0, stream>>>(
      Woutb, attnT, nullptr, W2b, nullptr);

  gemm128<3><<<dim3(1024), dim3(256), 0, stream>>>(
      v_tok, W2b, out, nullptr, bout);
}